// Round 1
// baseline (1891.122 us; speedup 1.0000x reference)
//
#include <hip/hip_runtime.h>

#define NN 2048
#define NE 32768
#define DIM 256
#define NH 4

// ---------------- A-operand descriptor (supports concat segments + row gather) ----
struct AD {
  const float* p[4];
  const int*   idx[4];   // nullptr -> identity; idx[m] < 0 -> zero row
  int ld[4];
  int nseg;              // >1 => each segment is 256 wide
  int kstride;           // element stride along K (within a row)
  int koff;              // constant element offset within a row
  long aoffz;            // element offset added per blockIdx.z
};

__device__ __forceinline__ unsigned f2ord(float f) {
  unsigned u = __float_as_uint(f);
  return (u & 0x80000000u) ? ~u : (u | 0x80000000u);
}
__device__ __forceinline__ float ord2f(unsigned k) {
  unsigned u = (k & 0x80000000u) ? (k ^ 0x80000000u) : ~k;
  return __uint_as_float(u);
}

__device__ __forceinline__ float dmask_eval(const float* __restrict__ C3,
    const float* __restrict__ W1, const float* __restrict__ b1,
    const float* __restrict__ W2, const float* __restrict__ b2,
    int n, int m, int h)
{
  float dx = C3[3*n+0] - C3[3*m+0];
  float dy = C3[3*n+1] - C3[3*m+1];
  float dz = C3[3*n+2] - C3[3*m+2];
  float sq = dx*dx + dy*dy + dz*dz;
  float dist = sq > 0.f ? sqrtf(sq) : 0.f;
  float o = b2[h];
  #pragma unroll
  for (int j = 0; j < 3; ++j) {
    float hd = b1[j] + dx*W1[0*3+j] + dy*W1[1*3+j] + dz*W1[2*3+j] + dist*W1[3*3+j];
    hd = fmaxf(hd, 0.f);
    o += hd * W2[j*4+h];
  }
  return o;
}

// ---------------- generic fp32 tiled GEMM: C = epi(scale*A@B + bias) -------------
// EPI: 0=none 1=relu 2=sigmoid 3=+dmask(row,col,z)
template<int EPI>
__global__ __launch_bounds__(256) void gemm_k(
    AD a, const float* __restrict__ B, int ldbk, int ldbj, long boffz,
    const float* __restrict__ bias, float* __restrict__ C, int ldc, long coffz,
    int K, float scale,
    const float* __restrict__ C3, const float* __restrict__ gW1, const float* __restrict__ gb1,
    const float* __restrict__ gW2, const float* __restrict__ gb2)
{
  __shared__ __align__(16) float As[16][68];
  __shared__ __align__(16) float Bs[16][68];
  const int tid = threadIdx.x;
  const int bz = blockIdx.z;
  const int m0 = blockIdx.y * 64;
  const int n0 = blockIdx.x * 64;
  const int tx = tid & 15, ty = tid >> 4;   // also reused as (k, m) for A staging
  const int bj = tid & 63, bk = tid >> 6;
  const long aoff = a.aoffz * bz;
  const long boff = boffz * bz;
  float acc[4][4] = {};

  for (int k0 = 0; k0 < K; k0 += 16) {
    int seg, kin0;
    if (a.nseg > 1) { seg = k0 >> 8; kin0 = (k0 & 255); } else { seg = 0; kin0 = k0; }
    const float* ap = a.p[seg];
    const int*   ix = a.idx[seg];
    const int   ald = a.ld[seg];
    const long kterm = (long)(kin0 + tx) * a.kstride + a.koff + aoff;
    #pragma unroll
    for (int pass = 0; pass < 4; ++pass) {
      int m = m0 + ty + pass*16;
      int r = ix ? ix[m] : m;
      float v = 0.f;
      if (r >= 0) v = ap[(long)r * ald + kterm];
      As[tx][ty + pass*16] = v;
    }
    #pragma unroll
    for (int pass = 0; pass < 4; ++pass) {
      int kk = bk + pass*4;
      Bs[kk][bj] = B[boff + (long)(k0+kk)*ldbk + (long)(n0+bj)*ldbj];
    }
    __syncthreads();
    #pragma unroll
    for (int kk = 0; kk < 16; ++kk) {
      float4 av = *(const float4*)&As[kk][ty*4];
      float4 bv = *(const float4*)&Bs[kk][tx*4];
      float aa[4] = {av.x, av.y, av.z, av.w};
      float bb[4] = {bv.x, bv.y, bv.z, bv.w};
      #pragma unroll
      for (int i = 0; i < 4; ++i)
        #pragma unroll
        for (int j = 0; j < 4; ++j)
          acc[i][j] = fmaf(aa[i], bb[j], acc[i][j]);
    }
    __syncthreads();
  }

  #pragma unroll
  for (int i = 0; i < 4; ++i) {
    int m = m0 + ty*4 + i;
    float vv[4];
    #pragma unroll
    for (int j = 0; j < 4; ++j) {
      int col = n0 + tx*4 + j;
      float v = acc[i][j] * scale;
      if (bias) v += bias[col];
      if constexpr (EPI == 1) v = fmaxf(v, 0.f);
      if constexpr (EPI == 2) v = 1.f / (1.f + expf(-v));
      if constexpr (EPI == 3) v += dmask_eval(C3, gW1, gb1, gW2, gb2, m, col, bz);
      vv[j] = v;
    }
    float4 o; o.x = vv[0]; o.y = vv[1]; o.z = vv[2]; o.w = vv[3];
    *(float4*)&C[coffz*bz + (long)m*ldc + n0 + tx*4] = o;
  }
}

// ---------------- helpers ---------------------------------------------------------
__global__ __launch_bounds__(256) void trans_k_kernel(const float* __restrict__ src,
                                                      float* __restrict__ dst) {
  // src [NN][DIM] -> dst [DIM][NN]
  __shared__ float t[32][33];
  int bm = blockIdx.x * 32, bc = blockIdx.y * 32;
  int tx = threadIdx.x & 31, ty = threadIdx.x >> 5;
  #pragma unroll
  for (int i = ty; i < 32; i += 8) t[i][tx] = src[(long)(bm+i)*DIM + bc + tx];
  __syncthreads();
  #pragma unroll
  for (int i = ty; i < 32; i += 8) dst[(long)(bc+i)*NN + bm + tx] = t[tx][i];
}

__global__ __launch_bounds__(256) void seg_sum_k(const float* __restrict__ ef,
    const int* __restrict__ ei, float* sub, float* obj, float* cs, float* cd) {
  int e = blockIdx.x * 4 + (threadIdx.x >> 6);
  int lane = threadIdx.x & 63;
  int s = ei[e], d = ei[NE + e];
  const float* row = ef + (long)e * DIM;
  #pragma unroll
  for (int c = 0; c < 4; ++c) {
    float v = row[lane + c*64];
    atomicAdd(&sub[(long)s*DIM + lane + c*64], v);
    atomicAdd(&obj[(long)d*DIM + lane + c*64], v);
  }
  if (lane == 0) { atomicAdd(&cs[s], 1.f); atomicAdd(&cd[d], 1.f); }
}

__global__ void seg_norm_k(float* sub, float* obj, const float* cs, const float* cd) {
  int n = blockIdx.x, t = threadIdx.x;
  float is = 1.f / fmaxf(cs[n], 1.f);
  float id = 1.f / fmaxf(cd[n], 1.f);
  sub[(long)n*DIM + t] *= is;
  obj[(long)n*DIM + t] *= id;
}

__global__ __launch_bounds__(256) void softmax_k(float* __restrict__ S) {
  long base = (long)blockIdx.x * NN;
  int t = threadIdx.x;
  float v[8];
  float mx = -1e30f;
  #pragma unroll
  for (int i = 0; i < 8; ++i) { v[i] = S[base + t + i*256]; mx = fmaxf(mx, v[i]); }
  #pragma unroll
  for (int off = 32; off; off >>= 1) mx = fmaxf(mx, __shfl_xor(mx, off));
  __shared__ float r1[4], r2[4];
  if ((t & 63) == 0) r1[t >> 6] = mx;
  __syncthreads();
  mx = fmaxf(fmaxf(r1[0], r1[1]), fmaxf(r1[2], r1[3]));
  float sum = 0.f;
  #pragma unroll
  for (int i = 0; i < 8; ++i) { v[i] = expf(v[i] - mx); sum += v[i]; }
  #pragma unroll
  for (int off = 32; off; off >>= 1) sum += __shfl_xor(sum, off);
  if ((t & 63) == 0) r2[t >> 6] = sum;
  __syncthreads();
  sum = r2[0] + r2[1] + r2[2] + r2[3];
  float inv = 1.f / sum;
  #pragma unroll
  for (int i = 0; i < 8; ++i) S[base + t + i*256] = v[i] * inv;
}

__global__ void node_out_k(const float* mh, const float* ea, float* out) {
  long i = (long)blockIdx.x * 256 + threadIdx.x;
  out[i] = fmaxf(mh[i], 0.f) * ea[i];
}

__global__ void scat_k(const int* ei, int* tbl) {
  int e = blockIdx.x * 256 + threadIdx.x;
  atomicMax(&tbl[(long)ei[e] * NN + ei[NE + e]], e + 1);
}

__global__ void rev_k(const int* ei, const int* tbl, int* rev) {
  int e = blockIdx.x * 256 + threadIdx.x;
  rev[e] = tbl[(long)ei[NE + e] * NN + ei[e]] - 1;
}

__global__ void fill_k(unsigned* p, unsigned v) {
  p[(long)blockIdx.x * 256 + threadIdx.x] = v;
}

__global__ __launch_bounds__(256) void msg_k(const float* __restrict__ Sb,
    const float* __restrict__ val, const int* __restrict__ ei, unsigned* __restrict__ aggk) {
  int e = blockIdx.x;
  int h = threadIdx.x >> 6, lane = threadIdx.x & 63;
  float s = Sb[(long)h * NE * 64 + (long)e * 64 + lane];
  float mx = s;
  #pragma unroll
  for (int off = 32; off; off >>= 1) mx = fmaxf(mx, __shfl_xor(mx, off));
  float p = expf(s - mx), sum = p;
  #pragma unroll
  for (int off = 32; off; off >>= 1) sum += __shfl_xor(sum, off);
  float m = (p / sum) * val[(long)e * DIM + lane*4 + h];
  atomicMax(&aggk[(long)ei[e] * DIM + lane*4 + h], f2ord(m));
}

__global__ void aggdec_k(unsigned* aggk) {
  long i = (long)blockIdx.x * 256 + threadIdx.x;
  float v = ord2f(aggk[i]);
  unsigned b = __float_as_uint(v);
  ((float*)aggk)[i] = ((b & 0x7F800000u) == 0x7F800000u) ? 0.f : v;
}

// ---------------- host side -------------------------------------------------------
static AD ad1(const float* p, int ld) {
  AD a{};
  a.p[0] = p; a.idx[0] = nullptr; a.ld[0] = ld;
  a.nseg = 1; a.kstride = 1; a.koff = 0; a.aoffz = 0;
  return a;
}

static void launch_gemm(hipStream_t st, int epi, const AD& a,
    const float* B, int ldbk, int ldbj, long boffz,
    const float* bias, float* C, int ldc, long coffz,
    int M, int N, int K, int Z, float scale,
    const float* C3, const float* g1, const float* gb1, const float* g2, const float* gb2)
{
  dim3 grid((unsigned)(N / 64), (unsigned)(M / 64), (unsigned)Z);
  switch (epi) {
    case 0: hipLaunchKernelGGL((gemm_k<0>), grid, dim3(256), 0, st, a, B, ldbk, ldbj, boffz, bias, C, ldc, coffz, K, scale, C3, g1, gb1, g2, gb2); break;
    case 1: hipLaunchKernelGGL((gemm_k<1>), grid, dim3(256), 0, st, a, B, ldbk, ldbj, boffz, bias, C, ldc, coffz, K, scale, C3, g1, gb1, g2, gb2); break;
    case 2: hipLaunchKernelGGL((gemm_k<2>), grid, dim3(256), 0, st, a, B, ldbk, ldbj, boffz, bias, C, ldc, coffz, K, scale, C3, g1, gb1, g2, gb2); break;
    default: hipLaunchKernelGGL((gemm_k<3>), grid, dim3(256), 0, st, a, B, ldbk, ldbj, boffz, bias, C, ldc, coffz, K, scale, C3, g1, gb1, g2, gb2); break;
  }
}

extern "C" void kernel_launch(void* const* d_in, const int* in_sizes, int n_in,
                              void* d_out, int out_size, void* d_ws, size_t ws_size,
                              hipStream_t stream) {
  (void)in_sizes; (void)n_in; (void)out_size; (void)ws_size;

  const float* node_f = (const float*)d_in[0];
  const float* edge_f = (const float*)d_in[1];
  const float* coords = (const float*)d_in[2];
  const int*   ei     = (const int*)d_in[3];
  const float* Wq = (const float*)d_in[5];  const float* bq = (const float*)d_in[6];
  const float* Wk = (const float*)d_in[7];  const float* bk = (const float*)d_in[8];
  const float* Wv = (const float*)d_in[9];  const float* bv = (const float*)d_in[10];
  const float* Wo = (const float*)d_in[11]; const float* bo = (const float*)d_in[12];
  const float* gd_W1 = (const float*)d_in[13]; const float* gd_b1 = (const float*)d_in[14];
  const float* gd_W2 = (const float*)d_in[15]; const float* gd_b2 = (const float*)d_in[16];
  const float* tw_W1 = (const float*)d_in[17]; const float* tw_b1 = (const float*)d_in[18];
  const float* tw_W2 = (const float*)d_in[19]; const float* tw_b2 = (const float*)d_in[20];
  const float* ne_W1 = (const float*)d_in[21]; const float* ne_b1 = (const float*)d_in[22];
  const float* ne_W2 = (const float*)d_in[23]; const float* ne_b2 = (const float*)d_in[24];
  const float* att_W1 = (const float*)d_in[25]; const float* att_b1 = (const float*)d_in[26];
  const float* att_W2 = (const float*)d_in[27]; const float* att_b2 = (const float*)d_in[28];
  const float* pe_W = (const float*)d_in[29]; const float* pe_b = (const float*)d_in[30];
  const float* pq_W = (const float*)d_in[31]; const float* pq_b = (const float*)d_in[32];
  const float* pv_W = (const float*)d_in[33]; const float* pv_b = (const float*)d_in[34];
  const float* pr_W1 = (const float*)d_in[35]; const float* pr_b1 = (const float*)d_in[36];
  const float* pr_W2 = (const float*)d_in[37]; const float* pr_b2 = (const float*)d_in[38];

  float* ws = (float*)d_ws;
  float* out = (float*)d_out;

  // -------- workspace layout (floats), with time-unioned big regions --------
  const long o_q    = 0;
  const long o_k    = o_q    + (long)NN*DIM;
  const long o_v    = o_k    + (long)NN*DIM;
  const long o_kT   = o_v    + (long)NN*DIM;
  const long o_attn = o_kT   + (long)NN*DIM;
  const long o_mhsa = o_attn + (long)NN*DIM;
  const long o_sub  = o_mhsa + (long)NN*DIM;
  const long o_obj  = o_sub  + (long)NN*DIM;
  const long o_twh  = o_obj  + (long)NN*DIM;
  const long o_eatt = o_twh  + (long)NN*DIM;
  const long o_agg  = o_eatt + (long)NN*DIM;
  const long o_cs   = o_agg  + (long)NN*DIM;
  const long o_cd   = o_cs   + NN;
  const long o_rev  = o_cd   + NN;
  const long o_prh  = o_rev  + NE;
  const long o_tbl  = o_prh  + (long)NN*512;        // table [NN*NN] ints, later H1 [NE*128]
  const long o_S    = o_tbl  + (long)NN*NN;         // S_all [4*NN*NN], later nehid/qe [NE*512]
  const long o_val  = o_S    + 4L*NN*NN;
  const long o_sb   = o_val  + (long)NE*DIM;        // Sbuf [4][NE][64]

  float* q    = ws + o_q;
  float* kbuf = ws + o_k;
  float* vbuf = ws + o_v;
  float* kT   = ws + o_kT;
  float* attn = ws + o_attn;
  float* mhsa = ws + o_mhsa;
  float* sub  = ws + o_sub;
  float* obj  = ws + o_obj;
  float* twh  = ws + o_twh;
  float* eatt = ws + o_eatt;
  float* prh  = ws + o_prh;
  int*   tbl  = (int*)(ws + o_tbl);
  float* H1   = ws + o_tbl;        // reuse after rev computed
  float* S    = ws + o_S;          // scores, then ne hidden, then qe
  float* nehid = ws + o_S;
  float* qe   = ws + o_S;
  float* valb = ws + o_val;
  float* Sb   = ws + o_sb;
  int*   rev  = (int*)(ws + o_rev);
  unsigned* aggk = (unsigned*)(ws + o_agg);

  float* out_node = out;
  float* out_edge = out + (long)NN*DIM;
  float* out_xx   = out + (long)NN*DIM + (long)NE*DIM;

  // -------- init --------
  hipMemsetAsync(sub, 0, 2L*NN*DIM*sizeof(float), stream);       // sub + obj (contiguous)
  hipMemsetAsync(ws + o_cs, 0, 2L*NN*sizeof(float), stream);      // cs + cd
  hipMemsetAsync(tbl, 0, (long)NN*NN*sizeof(int), stream);
  fill_k<<<(NN*DIM)/256, 256, 0, stream>>>(aggk, 0x007FFFFFu);    // f2ord(-inf)

  // -------- twin edge-mean gate --------
  seg_sum_k<<<NE/4, 256, 0, stream>>>(edge_f, ei, sub, obj, ws + o_cs, ws + o_cd);
  seg_norm_k<<<NN, 256, 0, stream>>>(sub, obj, ws + o_cs, ws + o_cd);

  AD a{};
  a.p[0] = sub; a.p[1] = obj; a.ld[0] = a.ld[1] = DIM;
  a.nseg = 2; a.kstride = 1; a.koff = 0; a.aoffz = 0;
  launch_gemm(stream, 1, a, tw_W1, DIM, 1, 0, tw_b1, twh, DIM, 0, NN, DIM, 512, 1, 1.f, nullptr, nullptr, nullptr, nullptr, nullptr);
  a = ad1(twh, DIM);
  launch_gemm(stream, 2, a, tw_W2, DIM, 1, 0, tw_b2, eatt, DIM, 0, NN, DIM, DIM, 1, 1.f, nullptr, nullptr, nullptr, nullptr, nullptr);

  // -------- MHSA --------
  a = ad1(node_f, DIM);
  launch_gemm(stream, 0, a, Wq, DIM, 1, 0, bq, q, DIM, 0, NN, DIM, DIM, 1, 1.f, nullptr, nullptr, nullptr, nullptr, nullptr);
  launch_gemm(stream, 0, a, Wk, DIM, 1, 0, bk, kbuf, DIM, 0, NN, DIM, DIM, 1, 1.f, nullptr, nullptr, nullptr, nullptr, nullptr);
  launch_gemm(stream, 0, a, Wv, DIM, 1, 0, bv, vbuf, DIM, 0, NN, DIM, DIM, 1, 1.f, nullptr, nullptr, nullptr, nullptr, nullptr);

  trans_k_kernel<<<dim3(NN/32, DIM/32), 256, 0, stream>>>(kbuf, kT);

  a = ad1(q, DIM); a.aoffz = 64;                       // per-head q slice
  launch_gemm(stream, 3, a, kT, NN, 1, 64L*NN, nullptr, S, NN, (long)NN*NN,
              NN, NN, 64, NH, 0.125f, coords, gd_W1, gd_b1, gd_W2, gd_b2);

  softmax_k<<<NN*NH, 256, 0, stream>>>(S);

  a = ad1(S, NN); a.aoffz = (long)NN*NN;
  launch_gemm(stream, 0, a, vbuf, DIM, 1, 64, nullptr, attn, DIM, 64,
              NN, 64, NN, NH, 1.f, nullptr, nullptr, nullptr, nullptr, nullptr);

  a = ad1(attn, DIM);
  launch_gemm(stream, 0, a, Wo, DIM, 1, 0, bo, mhsa, DIM, 0, NN, DIM, DIM, 1, 1.f, nullptr, nullptr, nullptr, nullptr, nullptr);

  node_out_k<<<NN, 256, 0, stream>>>(mhsa, eatt, out_node);

  // -------- reverse-edge lookup --------
  scat_k<<<NE/256, 256, 0, stream>>>(ei, tbl);
  rev_k<<<NE/256, 256, 0, stream>>>(ei, tbl, rev);

  // -------- edge MLP (dominant GEMM) --------
  a = AD{};
  a.nseg = 4; a.kstride = 1; a.koff = 0; a.aoffz = 0;
  a.p[0] = node_f; a.idx[0] = ei;        a.ld[0] = DIM;   // x_i = node_f[src]
  a.p[1] = edge_f; a.idx[1] = nullptr;   a.ld[1] = DIM;   // edge_f
  a.p[2] = edge_f; a.idx[2] = rev;       a.ld[2] = DIM;   // rev_feat (or 0)
  a.p[3] = node_f; a.idx[3] = ei + NE;   a.ld[3] = DIM;   // x_j = node_f[dst]
  launch_gemm(stream, 1, a, ne_W1, 512, 1, 0, ne_b1, nehid, 512, 0, NE, 512, 1024, 1, 1.f, nullptr, nullptr, nullptr, nullptr, nullptr);
  a = ad1(nehid, 512);
  launch_gemm(stream, 0, a, ne_W2, DIM, 1, 0, ne_b2, out_edge, DIM, 0, NE, DIM, 512, 1, 1.f, nullptr, nullptr, nullptr, nullptr, nullptr);

  // -------- per-edge attention projections (qe region reuses nehid region) --------
  a = ad1(node_f, DIM); a.idx[0] = ei + NE;
  launch_gemm(stream, 0, a, pv_W, DIM, 1, 0, pv_b, valb, DIM, 0, NE, DIM, DIM, 1, 1.f, nullptr, nullptr, nullptr, nullptr, nullptr);
  a = ad1(node_f, DIM); a.idx[0] = ei;
  launch_gemm(stream, 0, a, pq_W, DIM, 1, 0, pq_b, qe, 512, 0, NE, DIM, DIM, 1, 1.f, nullptr, nullptr, nullptr, nullptr, nullptr);
  a = ad1(edge_f, DIM);
  launch_gemm(stream, 0, a, pe_W, DIM, 1, 0, pe_b, qe + DIM, 512, 0, NE, DIM, DIM, 1, 1.f, nullptr, nullptr, nullptr, nullptr, nullptr);

  // per head: h1 = relu(qe_h @ W1^T + b1); s = h1 @ W2^T + b2
  for (int h = 0; h < NH; ++h) {
    AD ah = ad1(qe, 512); ah.kstride = 4; ah.koff = h;
    launch_gemm(stream, 1, ah, att_W1, 1, 128, 0, att_b1, H1, 128, 0, NE, 128, 128, 1, 1.f, nullptr, nullptr, nullptr, nullptr, nullptr);
    AD a2 = ad1(H1, 128);
    launch_gemm(stream, 0, a2, att_W2, 1, 128, 0, att_b2, Sb + (long)h*NE*64, 64, 0, NE, 64, 128, 1, 1.f, nullptr, nullptr, nullptr, nullptr, nullptr);
  }

  msg_k<<<NE, 256, 0, stream>>>(Sb, valb, ei, aggk);
  aggdec_k<<<(NN*DIM)/256, 256, 0, stream>>>(aggk);

  // -------- final node MLP --------
  a = AD{};
  a.nseg = 2; a.kstride = 1; a.koff = 0; a.aoffz = 0;
  a.p[0] = node_f;        a.idx[0] = nullptr; a.ld[0] = DIM;
  a.p[1] = (float*)aggk;  a.idx[1] = nullptr; a.ld[1] = DIM;
  launch_gemm(stream, 1, a, pr_W1, 512, 1, 0, pr_b1, prh, 512, 0, NN, 512, 512, 1, 1.f, nullptr, nullptr, nullptr, nullptr, nullptr);
  a = ad1(prh, 512);
  launch_gemm(stream, 0, a, pr_W2, DIM, 1, 0, pr_b2, out_xx, DIM, 0, NN, DIM, 512, 1, 1.f, nullptr, nullptr, nullptr, nullptr, nullptr);
}

// Round 2
// 634.960 us; speedup vs baseline: 2.9783x; 2.9783x over previous
//
#include <hip/hip_runtime.h>

#define NN 2048
#define NE 32768
#define DIM 256
#define NH 4

typedef unsigned short u16;
typedef __attribute__((ext_vector_type(4))) unsigned short u16x4;
typedef __attribute__((ext_vector_type(8))) short bf16x8;
typedef __attribute__((ext_vector_type(4))) float f32x4;

typedef __attribute__((address_space(1))) const unsigned int g_as1;
typedef __attribute__((address_space(3))) unsigned int l_as3;

__device__ __forceinline__ void gload16(const u16* g, u16* l) {
  __builtin_amdgcn_global_load_lds((g_as1*)g, (l_as3*)l, 16, 0, 0);
}

__device__ __forceinline__ u16 f2bf(float f) {
  unsigned u = __float_as_uint(f);
  unsigned r = u + 0x7FFFu + ((u >> 16) & 1u);
  return (u16)(r >> 16);
}

__device__ __forceinline__ unsigned f2ord(float f) {
  unsigned u = __float_as_uint(f);
  return (u & 0x80000000u) ? ~u : (u | 0x80000000u);
}
__device__ __forceinline__ float ord2f(unsigned k) {
  unsigned u = (k & 0x80000000u) ? (k ^ 0x80000000u) : ~k;
  return __uint_as_float(u);
}

__device__ __forceinline__ float dmask_eval(const float* __restrict__ C3,
    const float* __restrict__ W1, const float* __restrict__ b1,
    const float* __restrict__ W2, const float* __restrict__ b2,
    int n, int m, int h)
{
  float dx = C3[3*n+0] - C3[3*m+0];
  float dy = C3[3*n+1] - C3[3*m+1];
  float dz = C3[3*n+2] - C3[3*m+2];
  float sq = dx*dx + dy*dy + dz*dz;
  float dist = sq > 0.f ? sqrtf(sq) : 0.f;
  float o = b2[h];
  #pragma unroll
  for (int j = 0; j < 3; ++j) {
    float hd = b1[j] + dx*W1[0*3+j] + dy*W1[1*3+j] + dz*W1[2*3+j] + dist*W1[3*3+j];
    hd = fmaxf(hd, 0.f);
    o += hd * W2[j*4+h];
  }
  return o;
}

// ---------------- bf16 MFMA GEMM ------------------------------------------------
// C[m][n] = epi(scale * sum_k A[m][k]*Bt[n][k] + bias[n])
// Tiles: BM=128, BN=32*BNF, BK=64. 4 waves (2x2). LDS XOR-swizzled (T2),
// staged via global_load_lds width=16 with pre-swizzled source (rule #21).
struct GB { const u16* A; const int* idx; long ld; long aoffz; };

// EPI: 0 = f32 out; 1 = relu -> bf16; 2 = sigmoid -> f32; 3 = +dmask -> f32;
//      4 = headsplit bf16 (coffz = col-offset within head row); 5 = bf16 out
template<int BNF, int EPI>
__global__ __launch_bounds__(256) void gemm_bf(
    GB ga, const u16* __restrict__ Bt, long bld, long boffz,
    const float* __restrict__ bias, void* __restrict__ Cp, long ldc, long coffz,
    int K, float scale,
    const float* __restrict__ C3, const float* __restrict__ gW1, const float* __restrict__ gb1,
    const float* __restrict__ gW2, const float* __restrict__ gb2)
{
  __shared__ u16 As[128 * 64];
  __shared__ u16 Bs[32 * BNF * 64];

  const int tid = threadIdx.x;
  const int wid = tid >> 6, lane = tid & 63;
  const int bz = blockIdx.z;
  const int m0 = blockIdx.y * 128;
  const int n0 = blockIdx.x * (32 * BNF);
  const int wr = wid >> 1, wc = wid & 1;
  const int l15 = lane & 15, l4 = lane >> 4;

  // precompute staging source pointers (pre-swizzled: rule #21)
  const u16* asrc[4];
  #pragma unroll
  for (int c = 0; c < 4; ++c) {
    int rl = c*32 + wid*8 + (lane >> 3);
    int row = ga.idx ? ga.idx[m0 + rl] : (m0 + rl);
    int c16s = (lane & 7) ^ (rl & 7);
    asrc[c] = ga.A + ga.aoffz * bz + (long)row * ga.ld + c16s * 8;
  }
  const u16* bsrc[BNF];
  #pragma unroll
  for (int c = 0; c < BNF; ++c) {
    int rl = c*32 + wid*8 + (lane >> 3);
    int c16s = (lane & 7) ^ (rl & 7);
    bsrc[c] = Bt + boffz * bz + (long)(n0 + rl) * bld + c16s * 8;
  }

  f32x4 acc[4][BNF] = {};

  for (int k0 = 0; k0 < K; k0 += 64) {
    #pragma unroll
    for (int c = 0; c < 4; ++c)
      gload16(asrc[c] + k0, &As[(c*32 + wid*8) * 64]);
    #pragma unroll
    for (int c = 0; c < BNF; ++c)
      gload16(bsrc[c] + k0, &Bs[(c*32 + wid*8) * 64]);
    __syncthreads();

    #pragma unroll
    for (int kk = 0; kk < 2; ++kk) {
      bf16x8 af[4], bfr[BNF];
      #pragma unroll
      for (int i = 0; i < 4; ++i) {
        int r = wr*64 + i*16 + l15;
        af[i] = *(const bf16x8*)&As[r*64 + (((kk*4 + l4) ^ (r & 7)) * 8)];
      }
      #pragma unroll
      for (int j = 0; j < BNF; ++j) {
        int r = wc*(16*BNF) + j*16 + l15;
        bfr[j] = *(const bf16x8*)&Bs[r*64 + (((kk*4 + l4) ^ (r & 7)) * 8)];
      }
      #pragma unroll
      for (int i = 0; i < 4; ++i)
        #pragma unroll
        for (int j = 0; j < BNF; ++j)
          acc[i][j] = __builtin_amdgcn_mfma_f32_16x16x32_bf16(af[i], bfr[j], acc[i][j], 0, 0, 0);
    }
    __syncthreads();
  }

  // epilogue: C/D map col=lane&15, row=(lane>>4)*4+reg (m89-verified)
  #pragma unroll
  for (int j = 0; j < BNF; ++j) {
    const int col = n0 + wc*(16*BNF) + j*16 + l15;
    const float bb = bias ? bias[col] : 0.f;
    #pragma unroll
    for (int i = 0; i < 4; ++i) {
      #pragma unroll
      for (int r = 0; r < 4; ++r) {
        const int m = m0 + wr*64 + i*16 + l4*4 + r;
        float v = acc[i][j][r] * scale + bb;
        if constexpr (EPI == 1) v = fmaxf(v, 0.f);
        if constexpr (EPI == 2) v = 1.f / (1.f + expf(-v));
        if constexpr (EPI == 3) v += dmask_eval(C3, gW1, gb1, gW2, gb2, m, col, bz);
        if constexpr (EPI == 0 || EPI == 2 || EPI == 3)
          ((float*)Cp)[coffz*bz + (long)m*ldc + col] = v;
        else if constexpr (EPI == 4)
          ((u16*)Cp)[((long)(col & 3) * NE + m) * ldc + (col >> 2) + coffz] = f2bf(v);
        else
          ((u16*)Cp)[coffz*bz + (long)m*ldc + col] = f2bf(v);
      }
    }
  }
}

// ---------------- pack / convert kernels ----------------------------------------
__global__ void conv4_k(const float* __restrict__ s, u16* __restrict__ d, long n4) {
  long i = (long)blockIdx.x * 256 + threadIdx.x;
  if (i >= n4) return;
  float4 v = ((const float4*)s)[i];
  u16x4 o = { f2bf(v.x), f2bf(v.y), f2bf(v.z), f2bf(v.w) };
  ((u16x4*)d)[i] = o;
}

// W [K][N] f32 -> Wt [N][K] bf16 (K,N multiples of 32)
__global__ __launch_bounds__(256) void transw_k(const float* __restrict__ W,
                                                u16* __restrict__ Wt, int K, int N) {
  __shared__ float t[32][33];
  int bk = blockIdx.x * 32, bn = blockIdx.y * 32;
  int tx = threadIdx.x & 31, ty = threadIdx.x >> 5;
  #pragma unroll
  for (int i = ty; i < 32; i += 8) t[i][tx] = W[(long)(bk + i) * N + bn + tx];
  __syncthreads();
  #pragma unroll
  for (int i = ty; i < 32; i += 8) Wt[(long)(bn + i) * K + bk + tx] = f2bf(t[tx][i]);
}

__global__ __launch_bounds__(256) void seg_sum_k(const float* __restrict__ ef,
    const int* __restrict__ ei, float* sub, float* obj, float* cs, float* cd) {
  int e = blockIdx.x * 4 + (threadIdx.x >> 6);
  int lane = threadIdx.x & 63;
  int s = ei[e], d = ei[NE + e];
  const float* row = ef + (long)e * DIM;
  #pragma unroll
  for (int c = 0; c < 4; ++c) {
    float v = row[lane + c*64];
    atomicAdd(&sub[(long)s*DIM + lane + c*64], v);
    atomicAdd(&obj[(long)d*DIM + lane + c*64], v);
  }
  if (lane == 0) { atomicAdd(&cs[s], 1.f); atomicAdd(&cd[d], 1.f); }
}

__global__ void pack_tw_k(const float* __restrict__ sub, const float* __restrict__ obj,
    const float* __restrict__ cs, const float* __restrict__ cd, u16* __restrict__ twA) {
  int n = blockIdx.x, t = threadIdx.x;  // 128 threads
  int seg = t >> 6, c = (t & 63) * 4;
  float sc = seg ? 1.f / fmaxf(cd[n], 1.f) : 1.f / fmaxf(cs[n], 1.f);
  float4 v = *(const float4*)((seg ? obj : sub) + (long)n * DIM + c);
  u16x4 o = { f2bf(v.x*sc), f2bf(v.y*sc), f2bf(v.z*sc), f2bf(v.w*sc) };
  *(u16x4*)&twA[(long)n*512 + seg*256 + c] = o;
}

__global__ void pack_ne_k(const float* __restrict__ nf, const float* __restrict__ ef,
    const int* __restrict__ ei, const int* __restrict__ rev, u16* __restrict__ neA) {
  int e = blockIdx.x, t = threadIdx.x;  // 256 threads
  int seg = t >> 6, c = (t & 63) * 4;
  const float* src;
  if (seg == 0)      src = nf + (long)ei[e] * DIM;
  else if (seg == 1) src = ef + (long)e * DIM;
  else if (seg == 2) { int r = rev[e]; src = (r >= 0) ? ef + (long)r * DIM : nullptr; }
  else               src = nf + (long)ei[NE + e] * DIM;
  float4 v;
  if (src) v = *(const float4*)(src + c);
  else { v.x = v.y = v.z = v.w = 0.f; }
  u16x4 o = { f2bf(v.x), f2bf(v.y), f2bf(v.z), f2bf(v.w) };
  *(u16x4*)&neA[(long)e*1024 + seg*256 + c] = o;
}

__global__ void pack_pr_k(const float* __restrict__ nf, const float* __restrict__ agg,
                          u16* __restrict__ prA) {
  int n = blockIdx.x, t = threadIdx.x;  // 128 threads
  int seg = t >> 6, c = (t & 63) * 4;
  float4 v = *(const float4*)((seg ? agg : nf) + (long)n * DIM + c);
  u16x4 o = { f2bf(v.x), f2bf(v.y), f2bf(v.z), f2bf(v.w) };
  *(u16x4*)&prA[(long)n*512 + seg*256 + c] = o;
}

__global__ __launch_bounds__(256) void softmax_k(const float* __restrict__ S,
                                                 u16* __restrict__ P) {
  long base = (long)blockIdx.x * NN;
  int t = threadIdx.x;
  float v[8];
  float mx = -1e30f;
  #pragma unroll
  for (int i = 0; i < 8; ++i) { v[i] = S[base + t + i*256]; mx = fmaxf(mx, v[i]); }
  #pragma unroll
  for (int off = 32; off; off >>= 1) mx = fmaxf(mx, __shfl_xor(mx, off));
  __shared__ float r1[4], r2[4];
  if ((t & 63) == 0) r1[t >> 6] = mx;
  __syncthreads();
  mx = fmaxf(fmaxf(r1[0], r1[1]), fmaxf(r1[2], r1[3]));
  float sum = 0.f;
  #pragma unroll
  for (int i = 0; i < 8; ++i) { v[i] = expf(v[i] - mx); sum += v[i]; }
  #pragma unroll
  for (int off = 32; off; off >>= 1) sum += __shfl_xor(sum, off);
  if ((t & 63) == 0) r2[t >> 6] = sum;
  __syncthreads();
  sum = r2[0] + r2[1] + r2[2] + r2[3];
  float inv = 1.f / sum;
  #pragma unroll
  for (int i = 0; i < 8; ++i) P[base + t + i*256] = f2bf(v[i] * inv);
}

__global__ void node_out_k(const float* mh, const float* ea, float* out) {
  long i = (long)blockIdx.x * 256 + threadIdx.x;
  out[i] = fmaxf(mh[i], 0.f) * ea[i];
}

__global__ void scat_k(const int* ei, int* tbl) {
  int e = blockIdx.x * 256 + threadIdx.x;
  atomicMax(&tbl[(long)ei[e] * NN + ei[NE + e]], e + 1);
}

__global__ void rev_k(const int* ei, const int* tbl, int* rev) {
  int e = blockIdx.x * 256 + threadIdx.x;
  rev[e] = tbl[(long)ei[NE + e] * NN + ei[e]] - 1;
}

__global__ void fill_k(unsigned* p, unsigned v) {
  p[(long)blockIdx.x * 256 + threadIdx.x] = v;
}

__global__ __launch_bounds__(256) void msg_k(const float* __restrict__ Sb,
    const float* __restrict__ val, const int* __restrict__ ei, unsigned* __restrict__ aggk) {
  int e = blockIdx.x;
  int h = threadIdx.x >> 6, lane = threadIdx.x & 63;
  float s = Sb[(long)h * NE * 64 + (long)e * 64 + lane];
  float mx = s;
  #pragma unroll
  for (int off = 32; off; off >>= 1) mx = fmaxf(mx, __shfl_xor(mx, off));
  float p = expf(s - mx), sum = p;
  #pragma unroll
  for (int off = 32; off; off >>= 1) sum += __shfl_xor(sum, off);
  float m = (p / sum) * val[(long)e * DIM + lane*4 + h];
  atomicMax(&aggk[(long)ei[e] * DIM + lane*4 + h], f2ord(m));
}

__global__ void aggdec_k(unsigned* aggk) {
  long i = (long)blockIdx.x * 256 + threadIdx.x;
  float v = ord2f(aggk[i]);
  unsigned b = __float_as_uint(v);
  ((float*)aggk)[i] = ((b & 0x7F800000u) == 0x7F800000u) ? 0.f : v;
}

// ---------------- host side ------------------------------------------------------
static GB gb(const u16* A, const int* idx, long ld, long aoffz) {
  GB g; g.A = A; g.idx = idx; g.ld = ld; g.aoffz = aoffz; return g;
}

extern "C" void kernel_launch(void* const* d_in, const int* in_sizes, int n_in,
                              void* d_out, int out_size, void* d_ws, size_t ws_size,
                              hipStream_t stream) {
  (void)in_sizes; (void)n_in; (void)out_size; (void)ws_size;

  const float* node_f = (const float*)d_in[0];
  const float* edge_f = (const float*)d_in[1];
  const float* coords = (const float*)d_in[2];
  const int*   ei     = (const int*)d_in[3];
  const float* Wq = (const float*)d_in[5];  const float* bq = (const float*)d_in[6];
  const float* Wk = (const float*)d_in[7];  const float* bk = (const float*)d_in[8];
  const float* Wv = (const float*)d_in[9];  const float* bv = (const float*)d_in[10];
  const float* Wo = (const float*)d_in[11]; const float* bo = (const float*)d_in[12];
  const float* gd_W1 = (const float*)d_in[13]; const float* gd_b1 = (const float*)d_in[14];
  const float* gd_W2 = (const float*)d_in[15]; const float* gd_b2 = (const float*)d_in[16];
  const float* tw_W1 = (const float*)d_in[17]; const float* tw_b1 = (const float*)d_in[18];
  const float* tw_W2 = (const float*)d_in[19]; const float* tw_b2 = (const float*)d_in[20];
  const float* ne_W1 = (const float*)d_in[21]; const float* ne_b1 = (const float*)d_in[22];
  const float* ne_W2 = (const float*)d_in[23]; const float* ne_b2 = (const float*)d_in[24];
  const float* att_W1 = (const float*)d_in[25]; const float* att_b1 = (const float*)d_in[26];
  const float* att_W2 = (const float*)d_in[27]; const float* att_b2 = (const float*)d_in[28];
  const float* pe_W = (const float*)d_in[29]; const float* pe_b = (const float*)d_in[30];
  const float* pq_W = (const float*)d_in[31]; const float* pq_b = (const float*)d_in[32];
  const float* pv_W = (const float*)d_in[33]; const float* pv_b = (const float*)d_in[34];
  const float* pr_W1 = (const float*)d_in[35]; const float* pr_b1 = (const float*)d_in[36];
  const float* pr_W2 = (const float*)d_in[37]; const float* pr_b2 = (const float*)d_in[38];

  char* WB = (char*)d_ws;
  float* out = (float*)d_out;
  float* out_node = out;
  float* out_edge = out + (long)NN*DIM;
  float* out_xx   = out + (long)NN*DIM + (long)NE*DIM;

  // -------- workspace: 4 big time-union'd regions + small region --------
  const long sz_R1 = 4L*NN*NN*4;   // 67.1 MB : S f32 -> neA bf16 -> valb f32
  const long sz_R2 = 4L*NN*NN*2;   // 33.5 MB : P_bf -> nehid bf16
  const long sz_R3 = 4L*NE*128*2;  // 33.5 MB : tbl int (16.8) + edge_bf (16.8) -> h1 bf16
  const long sz_R4 = 4L*NE*128*2;  // 33.5 MB : qeA bf16 -> Sb f32
  const long R1 = 0, R2 = R1 + sz_R1, R3 = R2 + sz_R2, R4 = R3 + sz_R3;

  float* S      = (float*)(WB + R1);
  u16*   neA    = (u16*)(WB + R1);
  float* valb   = (float*)(WB + R1);
  u16*   Pbf    = (u16*)(WB + R2);
  u16*   nehid  = (u16*)(WB + R2);
  int*   tbl    = (int*)(WB + R3);
  u16*   h1     = (u16*)(WB + R3);
  u16*   edge_bf= (u16*)(WB + R3 + (long)NN*NN*4);
  u16*   qeA    = (u16*)(WB + R4);
  float* Sb     = (float*)(WB + R4);

  long cur = R4 + sz_R4;
  auto alloc = [&](long bytes) { long o = cur; cur += (bytes + 255) & ~255L; return o; };

  long o_sub = alloc(2L*NN*DIM*4);          // sub+obj -> later q_bf,k_bf | vT,attn_bf
  float* sub = (float*)(WB + o_sub);
  float* obj = sub + (long)NN*DIM;
  u16* q_bf    = (u16*)sub;
  u16* k_bf    = q_bf + (long)NN*DIM;
  u16* vT      = (u16*)obj;
  u16* attn_bf = vT + (long)NN*DIM;

  long o_cs  = alloc(2L*NN*4);
  float* cs = (float*)(WB + o_cs); float* cd = cs + NN;
  long o_vb  = alloc((long)NN*DIM*4);       // vbuf -> later mhsa
  float* vbuf = (float*)(WB + o_vb);
  float* mhsa = vbuf;
  long o_ea  = alloc((long)NN*DIM*4);  float* eatt = (float*)(WB + o_ea);
  long o_ag  = alloc((long)NN*DIM*4);  unsigned* aggk = (unsigned*)(WB + o_ag);
  long o_rv  = alloc((long)NE*4);      int* rev = (int*)(WB + o_rv);
  long o_nbf = alloc((long)NN*DIM*2);  u16* node_bf = (u16*)(WB + o_nbf);
  long o_twA = alloc((long)NN*512*2);  u16* twA = (u16*)(WB + o_twA);
  long o_twh = alloc((long)NN*DIM*2);  u16* twh = (u16*)(WB + o_twh);
  long o_prA = alloc((long)NN*512*2);  u16* prA = (u16*)(WB + o_prA);
  long o_prh = alloc((long)NN*512*2);  u16* prh = (u16*)(WB + o_prh);

  u16* Wq_t  = (u16*)(WB + alloc(DIM*DIM*2));
  u16* Wk_t  = (u16*)(WB + alloc(DIM*DIM*2));
  u16* Wv_t  = (u16*)(WB + alloc(DIM*DIM*2));
  u16* Wo_t  = (u16*)(WB + alloc(DIM*DIM*2));
  u16* tw1_t = (u16*)(WB + alloc(DIM*512*2));
  u16* tw2_t = (u16*)(WB + alloc(DIM*DIM*2));
  u16* ne1_t = (u16*)(WB + alloc(512L*1024*2));
  u16* ne2_t = (u16*)(WB + alloc(DIM*512*2));
  u16* pe_t  = (u16*)(WB + alloc(DIM*DIM*2));
  u16* pq_t  = (u16*)(WB + alloc(DIM*DIM*2));
  u16* pv_t  = (u16*)(WB + alloc(DIM*DIM*2));
  u16* pr1_t = (u16*)(WB + alloc(512L*512*2));
  u16* pr2_t = (u16*)(WB + alloc(DIM*512*2));
  u16* a1_bf = (u16*)(WB + alloc(128*128*2));
  u16* a2_bf = (u16*)(WB + alloc(64*128*2));

  // -------- init --------
  hipMemsetAsync(sub, 0, 2L*NN*DIM*4, stream);
  hipMemsetAsync(cs, 0, 2L*NN*4, stream);
  hipMemsetAsync(tbl, 0, (long)NN*NN*4, stream);
  fill_k<<<(NN*DIM)/256, 256, 0, stream>>>(aggk, 0x007FFFFFu);  // f2ord(-inf)

  // -------- packs / weight converts --------
  seg_sum_k<<<NE/4, 256, 0, stream>>>(edge_f, ei, sub, obj, cs, cd);
  conv4_k<<<(NN*DIM/4+255)/256, 256, 0, stream>>>(node_f, node_bf, NN*DIM/4);
  conv4_k<<<(NE*DIM/4+255)/256, 256, 0, stream>>>(edge_f, edge_bf, (long)NE*DIM/4);
  conv4_k<<<(128*128/4+255)/256, 256, 0, stream>>>(att_W1, a1_bf, 128*128/4);
  conv4_k<<<(64*128/4+255)/256, 256, 0, stream>>>(att_W2, a2_bf, 64*128/4);
  transw_k<<<dim3(8,8),   256, 0, stream>>>(Wq, Wq_t, DIM, DIM);
  transw_k<<<dim3(8,8),   256, 0, stream>>>(Wk, Wk_t, DIM, DIM);
  transw_k<<<dim3(8,8),   256, 0, stream>>>(Wv, Wv_t, DIM, DIM);
  transw_k<<<dim3(8,8),   256, 0, stream>>>(Wo, Wo_t, DIM, DIM);
  transw_k<<<dim3(16,8),  256, 0, stream>>>(tw_W1, tw1_t, 512, DIM);
  transw_k<<<dim3(8,8),   256, 0, stream>>>(tw_W2, tw2_t, DIM, DIM);
  transw_k<<<dim3(32,16), 256, 0, stream>>>(ne_W1, ne1_t, 1024, 512);
  transw_k<<<dim3(16,8),  256, 0, stream>>>(ne_W2, ne2_t, 512, DIM);
  transw_k<<<dim3(8,8),   256, 0, stream>>>(pe_W, pe_t, DIM, DIM);
  transw_k<<<dim3(8,8),   256, 0, stream>>>(pq_W, pq_t, DIM, DIM);
  transw_k<<<dim3(8,8),   256, 0, stream>>>(pv_W, pv_t, DIM, DIM);
  transw_k<<<dim3(16,16), 256, 0, stream>>>(pr_W1, pr1_t, 512, 512);
  transw_k<<<dim3(16,8),  256, 0, stream>>>(pr_W2, pr2_t, 512, DIM);

  // -------- twin edge-mean gate --------
  pack_tw_k<<<NN, 128, 0, stream>>>(sub, obj, cs, cd, twA);
  gemm_bf<4,1><<<dim3(2,16,1), 256, 0, stream>>>(gb(twA, nullptr, 512, 0), tw1_t, 512, 0,
      tw_b1, twh, DIM, 0, 512, 1.f, nullptr, nullptr, nullptr, nullptr, nullptr);
  gemm_bf<4,2><<<dim3(2,16,1), 256, 0, stream>>>(gb(twh, nullptr, DIM, 0), tw2_t, DIM, 0,
      tw_b2, eatt, DIM, 0, DIM, 1.f, nullptr, nullptr, nullptr, nullptr, nullptr);

  // -------- MHSA --------
  gemm_bf<4,5><<<dim3(2,16,1), 256, 0, stream>>>(gb(node_bf, nullptr, DIM, 0), Wq_t, DIM, 0,
      bq, q_bf, DIM, 0, DIM, 1.f, nullptr, nullptr, nullptr, nullptr, nullptr);
  gemm_bf<4,5><<<dim3(2,16,1), 256, 0, stream>>>(gb(node_bf, nullptr, DIM, 0), Wk_t, DIM, 0,
      bk, k_bf, DIM, 0, DIM, 1.f, nullptr, nullptr, nullptr, nullptr, nullptr);
  gemm_bf<4,0><<<dim3(2,16,1), 256, 0, stream>>>(gb(node_bf, nullptr, DIM, 0), Wv_t, DIM, 0,
      bv, vbuf, DIM, 0, DIM, 1.f, nullptr, nullptr, nullptr, nullptr, nullptr);
  transw_k<<<dim3(64,8), 256, 0, stream>>>(vbuf, vT, NN, DIM);   // vT [256][2048] bf16

  gemm_bf<4,3><<<dim3(16,16,4), 256, 0, stream>>>(gb(q_bf, nullptr, DIM, 64), k_bf, DIM, 64,
      nullptr, S, NN, (long)NN*NN, 64, 0.125f, coords, gd_W1, gd_b1, gd_W2, gd_b2);
  softmax_k<<<NN*NH, 256, 0, stream>>>(S, Pbf);
  gemm_bf<2,5><<<dim3(1,16,4), 256, 0, stream>>>(gb(Pbf, nullptr, NN, (long)NN*NN), vT, NN, 64L*NN,
      nullptr, attn_bf, DIM, 64, NN, 1.f, nullptr, nullptr, nullptr, nullptr, nullptr);
  gemm_bf<4,0><<<dim3(2,16,1), 256, 0, stream>>>(gb(attn_bf, nullptr, DIM, 0), Wo_t, DIM, 0,
      bo, mhsa, DIM, 0, DIM, 1.f, nullptr, nullptr, nullptr, nullptr, nullptr);
  node_out_k<<<NN, 256, 0, stream>>>(mhsa, eatt, out_node);

  // -------- reverse-edge lookup + edge MLP --------
  scat_k<<<NE/256, 256, 0, stream>>>(ei, tbl);
  rev_k<<<NE/256, 256, 0, stream>>>(ei, tbl, rev);
  pack_ne_k<<<NE, 256, 0, stream>>>(node_f, edge_f, ei, rev, neA);   // R1 (S dead)
  gemm_bf<4,1><<<dim3(4,256,1), 256, 0, stream>>>(gb(neA, nullptr, 1024, 0), ne1_t, 1024, 0,
      ne_b1, nehid, 512, 0, 1024, 1.f, nullptr, nullptr, nullptr, nullptr, nullptr);  // R2 (Pbf dead)
  gemm_bf<4,0><<<dim3(2,256,1), 256, 0, stream>>>(gb(nehid, nullptr, 512, 0), ne2_t, 512, 0,
      ne_b2, out_edge, DIM, 0, 512, 1.f, nullptr, nullptr, nullptr, nullptr, nullptr);

  // -------- per-edge attention --------
  gemm_bf<4,0><<<dim3(2,256,1), 256, 0, stream>>>(gb(node_bf, ei + NE, DIM, 0), pv_t, DIM, 0,
      pv_b, valb, DIM, 0, DIM, 1.f, nullptr, nullptr, nullptr, nullptr, nullptr);     // R1 (neA dead)
  gemm_bf<4,4><<<dim3(2,256,1), 256, 0, stream>>>(gb(node_bf, ei, DIM, 0), pq_t, DIM, 0,
      pq_b, qeA, 128, 0, DIM, 1.f, nullptr, nullptr, nullptr, nullptr, nullptr);      // cols 0-63
  gemm_bf<4,4><<<dim3(2,256,1), 256, 0, stream>>>(gb(edge_bf, nullptr, DIM, 0), pe_t, DIM, 0,
      pe_b, qeA, 128, 64, DIM, 1.f, nullptr, nullptr, nullptr, nullptr, nullptr);     // cols 64-127
  gemm_bf<4,1><<<dim3(1,1024,1), 256, 0, stream>>>(gb(qeA, nullptr, 128, 0), a1_bf, 128, 0,
      att_b1, h1, 128, 0, 128, 1.f, nullptr, nullptr, nullptr, nullptr, nullptr);     // R3 (tbl,edge_bf dead)
  gemm_bf<2,0><<<dim3(1,1024,1), 256, 0, stream>>>(gb(h1, nullptr, 128, 0), a2_bf, 128, 0,
      att_b2, Sb, 64, 0, 128, 1.f, nullptr, nullptr, nullptr, nullptr, nullptr);      // R4 (qeA dead)

  msg_k<<<NE, 256, 0, stream>>>(Sb, valb, ei, aggk);
  aggdec_k<<<(NN*DIM)/256, 256, 0, stream>>>(aggk);

  // -------- final node MLP --------
  pack_pr_k<<<NN, 128, 0, stream>>>(node_f, (const float*)aggk, prA);
  gemm_bf<4,1><<<dim3(4,16,1), 256, 0, stream>>>(gb(prA, nullptr, 512, 0), pr1_t, 512, 0,
      pr_b1, prh, 512, 0, 512, 1.f, nullptr, nullptr, nullptr, nullptr, nullptr);
  gemm_bf<4,0><<<dim3(2,16,1), 256, 0, stream>>>(gb(prh, nullptr, 512, 0), pr2_t, 512, 0,
      pr_b2, out_xx, DIM, 0, 512, 1.f, nullptr, nullptr, nullptr, nullptr, nullptr);
}